// Round 17
// baseline (138.537 us; speedup 1.0000x reference)
//
#include <hip/hip_runtime.h>
#include <hip/hip_bf16.h>
#include <cmath>

#define NVP 250
#define NN  16000
#define EN  95232
#define LRc 0.01f
#define SQ2 1.41421356237309515f

#define CAP_ES 1024
#define CAP_N1 1024
#define CAP_E0 4096
#define EBLK ((EN + 255) / 256)   // 372
#define NBLK ((NN + 255) / 256)   // 63
#define SK_T 4
#define SK_GS 12

typedef __attribute__((ext_vector_type(8))) short bf16x8;
typedef __attribute__((ext_vector_type(4))) float f32x4;

__device__ __forceinline__ unsigned short bfc(float x) {
  unsigned u = __builtin_bit_cast(unsigned, x);
  u = (u + 0x7fffu + ((u >> 16) & 1u)) >> 16;   // RNE
  return (unsigned short)u;
}
__device__ __forceinline__ unsigned pk2(float a, float b) {
  return (unsigned)bfc(a) | ((unsigned)bfc(b) << 16);
}

// ---------------- fused epilogue params ----------------
struct FEP {
  const float* bias; float gain;
  const float* T0p; const float* la; const float* cnt; const float* w0n;  // EPI7
  const int* rmap; const int* dst; const int* posN;                        // EPI1/2/7
  float* outp; float* atomp;
};

// EPI 0: store outp. EPI 1: store + atomicAdd agg0c[posN[dst[rmap]]].
// EPI 2: atomicAdd agg1c[dst[rmap]/250]. EPI 7: +T0 +la*w0n, store.
template<int EPI>
__device__ __forceinline__ void mfma_epi(const FEP& f, f32x4 acc0, f32x4 acc1,
                                         f32x4 acc2, f32x4 acc3,
                                         int mBase, int nBase, int M,
                                         int lane, int wv) {
  const int fcol = lane & 15;
  int rows[4]; bool rok[4]; int tr[4];
  int rr4[4]; float la0[4], la1[4], la2[4]; bool has[4];
#pragma unroll
  for (int r = 0; r < 4; r++) {
    int row = mBase + wv*16 + (lane >> 4)*4 + r;
    rows[r] = row; rok[r] = row < M;
    int rc = rok[r] ? row : 0;
    if (EPI == 1) tr[r] = f.posN[f.dst[f.rmap[rc]]];
    if (EPI == 2) tr[r] = f.dst[f.rmap[rc]] / NVP;
    if (EPI == 7) {
      int nd = f.rmap[rc];
      rr4[r] = nd & 63;
      la0[r] = f.la[nd*3]; la1[r] = f.la[nd*3+1]; la2[r] = f.la[nd*3+2];
      has[r] = f.cnt[nd] > 0.f;
    }
  }
  f32x4 accs[4] = {acc0, acc1, acc2, acc3};
#pragma unroll
  for (int c = 0; c < 4; c++) {
    int n = nBase + fcol + 16*c;
    float bi = f.bias[n] * LRc;
    float w6[6];
    if (EPI == 7) {
#pragma unroll
      for (int j = 0; j < 6; j++) w6[j] = f.w0n[j*512 + n];
    }
#pragma unroll
    for (int r = 0; r < 4; r++) {
      if (!rok[r]) continue;
      float yr = accs[c][r];
      if (EPI == 7) {
#pragma unroll
        for (int zz = 0; zz < SK_T; zz++)
          yr += f.T0p[((size_t)zz*64 + rr4[r])*512 + n];
        float corr = la0[r]*w6[0] + la1[r]*w6[1] + la2[r]*w6[2];
        if (has[r]) corr += la0[r]*w6[3] + la1[r]*w6[4] + la2[r]*w6[5];
        yr += corr;
      }
      float y = yr * f.gain + bi;
      y = (y > 0.f ? y : 0.2f*y) * SQ2;
      if (EPI == 0 || EPI == 7) {
        f.outp[(size_t)rows[r]*512 + n] = y;
      } else if (EPI == 1) {
        f.outp[(size_t)rows[r]*512 + n] = y;
        atomicAdd(&f.atomp[(size_t)tr[r]*512 + n], y);
      } else { // 2
        atomicAdd(&f.atomp[(size_t)tr[r]*512 + n], y);
      }
    }
  }
}

// ---------------- LDS-staged bf16 MFMA GEMM, SK=1, fused epilogue ----------------
struct GMF {
  const float* W; const float* Ain; const int* Mdev;
  const float* cnt; const int* listN1;
  int Wld, Woff, Astride, K, Mcap, Mfix;
  FEP f;
};

template<int VECW, int SCALED, int EPI>
__global__ __launch_bounds__(256) void gemmMF(GMF p) {
  int M = p.Mdev ? *p.Mdev : p.Mfix;
  if (M > p.Mcap) M = p.Mcap;
  const int mBase = blockIdx.x * 64;
  if (mBase >= M) return;
  const int nBase = blockIdx.y * 64;

  __shared__ unsigned short Abf[64*72];
  __shared__ unsigned short Wbf[64*72];
  const int t = threadIdx.x;
  const int srow = t >> 2, sq = (t & 3) * 16;
  int arow = mBase + srow; if (arow >= M) arow = M - 1;
  float s = 1.f;
  if (SCALED) s = 1.0f / fmaxf(p.cnt[p.listN1[arow]], 1.0f);
  const float* aRow = p.Ain + (size_t)arow * p.Astride + sq;
  const float* wRow = p.W + (size_t)(nBase + srow) * p.Wld + p.Woff + sq;

  float4 ra[4], rw[4];
  auto ld = [&](int kt) {
#pragma unroll
    for (int i = 0; i < 4; i++) {
      ra[i] = *(const float4*)(aRow + kt + 4*i);
      if (VECW) {
        rw[i] = *(const float4*)(wRow + kt + 4*i);
      } else {
        const float* wp = wRow + kt + 4*i;
        rw[i] = make_float4(wp[0], wp[1], wp[2], wp[3]);
      }
    }
  };
  ld(0);

  const int lane = t & 63, wv = t >> 6;
  const int fr = wv*16 + (lane & 15);
  const int fcol = (lane & 15);
  const int fo = (lane >> 4) * 8;
  f32x4 acc0 = {}, acc1 = {}, acc2 = {}, acc3 = {};

  for (int kt = 0; kt < p.K; kt += 64) {
    if (kt > 0) __syncthreads();
    unsigned short* da = &Abf[srow*72 + sq];
    unsigned short* dw = &Wbf[srow*72 + sq];
#pragma unroll
    for (int i = 0; i < 4; i++) {
      uint2 ua; ua.x = pk2(ra[i].x*s, ra[i].y*s); ua.y = pk2(ra[i].z*s, ra[i].w*s);
      *(uint2*)&da[i*4] = ua;
      uint2 uw; uw.x = pk2(rw[i].x, rw[i].y); uw.y = pk2(rw[i].z, rw[i].w);
      *(uint2*)&dw[i*4] = uw;
    }
    __syncthreads();
    if (kt + 64 < p.K) ld(kt + 64);
#pragma unroll
    for (int kk = 0; kk < 64; kk += 32) {
      bf16x8 a = *(const bf16x8*)&Abf[fr*72 + kk + fo];
      bf16x8 b0 = *(const bf16x8*)&Wbf[( 0 + fcol)*72 + kk + fo];
      bf16x8 b1 = *(const bf16x8*)&Wbf[(16 + fcol)*72 + kk + fo];
      bf16x8 b2 = *(const bf16x8*)&Wbf[(32 + fcol)*72 + kk + fo];
      bf16x8 b3 = *(const bf16x8*)&Wbf[(48 + fcol)*72 + kk + fo];
      acc0 = __builtin_amdgcn_mfma_f32_16x16x32_bf16(a, b0, acc0, 0, 0, 0);
      acc1 = __builtin_amdgcn_mfma_f32_16x16x32_bf16(a, b1, acc1, 0, 0, 0);
      acc2 = __builtin_amdgcn_mfma_f32_16x16x32_bf16(a, b2, acc2, 0, 0, 0);
      acc3 = __builtin_amdgcn_mfma_f32_16x16x32_bf16(a, b3, acc3, 0, 0, 0);
    }
  }
  mfma_epi<EPI>(p.f, acc0, acc1, acc2, acc3, mBase, nBase, M, lane, wv);
}

// P1 edge L0, split-K MFMA gather: A row = [x1c[posN[src]]|x1c[posN[dst]]|ef0c[posOf]]
struct GGS {
  const float* W; const float* x1c; const float* ef0c;
  const int* listES; const int* src; const int* dst; const int* posN; const int* posOf;
  const int* Mdev; float* pbuf; int KC;
};
__global__ __launch_bounds__(256) void gemmGS(GGS p) {
  int M = *p.Mdev; if (M > CAP_ES) M = CAP_ES;
  const int mBase = blockIdx.x * 64;
  if (mBase >= M) return;
  const int nBase = blockIdx.y * 64;
  const int z = blockIdx.z;
  int kBeg = z * p.KC, kEnd = kBeg + p.KC;

  __shared__ unsigned short Abf[64*72];
  __shared__ unsigned short Wbf[64*72];
  const int t = threadIdx.x;
  const int srow = t >> 2, sq = (t & 3) * 16;
  int arow = mBase + srow; if (arow >= M) arow = M - 1;
  int e = p.listES[arow];
  const float* s0 = p.x1c + (size_t)p.posN[p.src[e]] * 512;
  const float* s1 = p.x1c + (size_t)p.posN[p.dst[e]] * 512;
  const float* s2 = p.ef0c + (size_t)p.posOf[e] * 512;
  const float* wRow = p.W + (size_t)(nBase + srow) * 1536 + sq;

  float4 ra[4], rw[4];
  auto ld = [&](int kt) {
    int ka = kt + sq;
    const float* ap = (ka < 512) ? (s0 + ka) : (ka < 1024) ? (s1 + ka - 512)
                                                           : (s2 + ka - 1024);
#pragma unroll
    for (int i = 0; i < 4; i++) {
      ra[i] = *(const float4*)(ap + 4*i);
      rw[i] = *(const float4*)(wRow + kt + 4*i);
    }
  };
  ld(kBeg);

  const int lane = t & 63, wv = t >> 6;
  const int fr = wv*16 + (lane & 15);
  const int fcol = (lane & 15);
  const int fo = (lane >> 4) * 8;
  f32x4 acc0 = {}, acc1 = {}, acc2 = {}, acc3 = {};

  for (int kt = kBeg; kt < kEnd; kt += 64) {
    if (kt > kBeg) __syncthreads();
    unsigned short* da = &Abf[srow*72 + sq];
    unsigned short* dw = &Wbf[srow*72 + sq];
#pragma unroll
    for (int i = 0; i < 4; i++) {
      uint2 ua; ua.x = pk2(ra[i].x, ra[i].y); ua.y = pk2(ra[i].z, ra[i].w);
      *(uint2*)&da[i*4] = ua;
      uint2 uw; uw.x = pk2(rw[i].x, rw[i].y); uw.y = pk2(rw[i].z, rw[i].w);
      *(uint2*)&dw[i*4] = uw;
    }
    __syncthreads();
    if (kt + 64 < kEnd) ld(kt + 64);
#pragma unroll
    for (int kk = 0; kk < 64; kk += 32) {
      bf16x8 a = *(const bf16x8*)&Abf[fr*72 + kk + fo];
      bf16x8 b0 = *(const bf16x8*)&Wbf[( 0 + fcol)*72 + kk + fo];
      bf16x8 b1 = *(const bf16x8*)&Wbf[(16 + fcol)*72 + kk + fo];
      bf16x8 b2 = *(const bf16x8*)&Wbf[(32 + fcol)*72 + kk + fo];
      bf16x8 b3 = *(const bf16x8*)&Wbf[(48 + fcol)*72 + kk + fo];
      acc0 = __builtin_amdgcn_mfma_f32_16x16x32_bf16(a, b0, acc0, 0, 0, 0);
      acc1 = __builtin_amdgcn_mfma_f32_16x16x32_bf16(a, b1, acc1, 0, 0, 0);
      acc2 = __builtin_amdgcn_mfma_f32_16x16x32_bf16(a, b2, acc2, 0, 0, 0);
      acc3 = __builtin_amdgcn_mfma_f32_16x16x32_bf16(a, b3, acc3, 0, 0, 0);
    }
  }
  float* ob = p.pbuf + (size_t)z * CAP_ES * 512;
  int orow = mBase + wv*16 + (lane >> 4) * 4;
  int oc = nBase + fcol;
#pragma unroll
  for (int r = 0; r < 4; r++) {
    float* q = ob + (size_t)(orow + r) * 512 + oc;
    q[0] = acc0[r]; q[16] = acc1[r]; q[32] = acc2[r]; q[48] = acc3[r];
  }
}

// epilogue for gemmGS: runtime-M, sum SK partials, activation, store hs
struct EPS {
  const float* pbuf; const float* bias; const int* Mdev;
  float* outp; int SK; float gain;
};
__global__ __launch_bounds__(256) void epiS_k(EPS e) {
  int M = *e.Mdev; if (M > CAP_ES) M = CAP_ES;
  int i = blockIdx.x*256 + threadIdx.x;
  if (i >= M*128) return;
  int m = i >> 7, n4 = (i & 127) * 4;
  float ys[4] = {0.f, 0.f, 0.f, 0.f};
  for (int z = 0; z < e.SK; z++) {
    float4 v = *(const float4*)&e.pbuf[((size_t)z*CAP_ES + m)*512 + n4];
    ys[0] += v.x; ys[1] += v.y; ys[2] += v.z; ys[3] += v.w;
  }
#pragma unroll
  for (int j = 0; j < 4; j++) {
    float y = ys[j] * e.gain + e.bias[n4+j] * LRc;
    ys[j] = (y > 0.f ? y : 0.2f*y) * SQ2;
  }
  *(float4*)&e.outp[(size_t)m*512 + n4] = make_float4(ys[0],ys[1],ys[2],ys[3]);
}

// ---------------- f32 pipelined GEMM loop ----------------
template<int VECW, int NSEG>
__device__ __forceinline__ void gemm_loop(
    const float* const* b0, const float* const* b1,
    const float* sc0, const float* sc1,
    const float* w0, const float* w1, const float* w2, const float* w3,
    int kBeg, int kEnd,
    float (*As)[36], float (*Bs)[68], float acc[4][4]) {
  const int t = threadIdx.x;
  const int k4 = (t & 7) * 4;
  const int mr = t >> 3;
  const int tx = t & 15, ty = t >> 4;
  float4 ra0, ra1, rw0, rw1, rw2, rw3;
  auto lA = [&](int k0) {
    int ka = k0 + k4;
    int idx = 0;
    if (NSEG >= 2 && ka >= 512) idx = 1;
    if (NSEG == 3 && ka >= 1024) idx = 2;
    float s0 = sc0[idx], s1 = sc1[idx];
    ra0 = *(const float4*)(b0[idx] + ka);
    ra1 = *(const float4*)(b1[idx] + ka);
    ra0.x *= s0; ra0.y *= s0; ra0.z *= s0; ra0.w *= s0;
    ra1.x *= s1; ra1.y *= s1; ra1.z *= s1; ra1.w *= s1;
  };
  auto lW = [&](int k0) {
    if (VECW) {
      rw0 = *(const float4*)(w0 + k0); rw1 = *(const float4*)(w1 + k0);
      rw2 = *(const float4*)(w2 + k0); rw3 = *(const float4*)(w3 + k0);
    } else {
      rw0 = make_float4(w0[k0], w0[k0+1], w0[k0+2], w0[k0+3]);
      rw1 = make_float4(w1[k0], w1[k0+1], w1[k0+2], w1[k0+3]);
      rw2 = make_float4(w2[k0], w2[k0+1], w2[k0+2], w2[k0+3]);
      rw3 = make_float4(w3[k0], w3[k0+1], w3[k0+2], w3[k0+3]);
    }
  };
  lA(kBeg); lW(kBeg);
  for (int k0 = kBeg; k0 < kEnd; k0 += 32) {
    if (k0 > kBeg) __syncthreads();
    As[k4+0][mr] = ra0.x; As[k4+1][mr] = ra0.y;
    As[k4+2][mr] = ra0.z; As[k4+3][mr] = ra0.w;
    As[k4+0][mr+16] = ra1.x; As[k4+1][mr+16] = ra1.y;
    As[k4+2][mr+16] = ra1.z; As[k4+3][mr+16] = ra1.w;
    Bs[k4+0][mr]    = rw0.x; Bs[k4+1][mr]    = rw0.y; Bs[k4+2][mr]    = rw0.z; Bs[k4+3][mr]    = rw0.w;
    Bs[k4+0][mr+16] = rw1.x; Bs[k4+1][mr+16] = rw1.y; Bs[k4+2][mr+16] = rw1.z; Bs[k4+3][mr+16] = rw1.w;
    Bs[k4+0][mr+32] = rw2.x; Bs[k4+1][mr+32] = rw2.y; Bs[k4+2][mr+32] = rw2.z; Bs[k4+3][mr+32] = rw2.w;
    Bs[k4+0][mr+48] = rw3.x; Bs[k4+1][mr+48] = rw3.y; Bs[k4+2][mr+48] = rw3.z; Bs[k4+3][mr+48] = rw3.w;
    __syncthreads();
    if (k0 + 32 < kEnd) { lA(k0 + 32); lW(k0 + 32); }
#pragma unroll
    for (int kk = 0; kk < 32; kk++) {
      float4 a4 = *(const float4*)&As[kk][ty*4];
      float4 b4 = *(const float4*)&Bs[kk][tx*4];
      float aa[4] = {a4.x, a4.y, a4.z, a4.w};
      float bb[4] = {b4.x, b4.y, b4.z, b4.w};
#pragma unroll
      for (int i = 0; i < 4; i++)
#pragma unroll
        for (int j = 0; j < 4; j++) acc[i][j] += aa[i]*bb[j];
    }
  }
}

// P1 node L0 (M=64, f32, split-K)
struct GTP {
  const float* W; const float* x1c; const float* agg1c; const float* cnt;
  const int* posN; float* pbuf; int KC;
};
__global__ __launch_bounds__(128) void gemmT(GTP p) {
  const int mBase = blockIdx.x * 32;
  const int nBase = blockIdx.y * 64;
  const int z = blockIdx.z;
  int kBeg = z * p.KC, kEnd = kBeg + p.KC;
  __shared__ float As[32][36];
  __shared__ float Bs[32][68];
  const int t = threadIdx.x;
  int r0 = mBase + (t>>3), r1 = r0 + 16;
  const float* b0[2] = { p.x1c + (size_t)p.posN[r0*NVP]*512,
                         p.agg1c + (size_t)r0*512 - 512 };
  const float* b1[2] = { p.x1c + (size_t)p.posN[r1*NVP]*512,
                         p.agg1c + (size_t)r1*512 - 512 };
  float sc0[2] = {1.f, 1.0f / fmaxf(p.cnt[r0*NVP], 1.0f)};
  float sc1[2] = {1.f, 1.0f / fmaxf(p.cnt[r1*NVP], 1.0f)};
  const int kofs = (t & 7)*4;
  const float* w0 = p.W + (size_t)(nBase + (t>>3)) * 1024 + kofs;
  const float* w1 = w0 + (size_t)16 * 1024;
  const float* w2 = w0 + (size_t)32 * 1024;
  const float* w3 = w0 + (size_t)48 * 1024;
  float acc[4][4] = {};
  gemm_loop<1, 2>(b0, b1, sc0, sc1, w0, w1, w2, w3, kBeg, kEnd, As, Bs, acc);
  const int tx = t & 15, ty = t >> 4;
#pragma unroll
  for (int i = 0; i < 4; i++) {
    int r = mBase + ty*4 + i;
    *(float4*)&p.pbuf[((size_t)z*64 + r)*512 + nBase + tx*4] =
      make_float4(acc[i][0],acc[i][1],acc[i][2],acc[i][3]);
  }
}

// P1 node L1 (M=64, f32, split-K)
struct GPP {
  const float* W; const float* Ain; float* pbuf; int KC;
};
__global__ __launch_bounds__(128) void gemmP(GPP p) {
  const int mBase = blockIdx.x * 32;
  const int nBase = blockIdx.y * 64;
  const int z = blockIdx.z;
  int kBeg = z * p.KC, kEnd = kBeg + p.KC;
  __shared__ float As[32][36];
  __shared__ float Bs[32][68];
  const int t = threadIdx.x;
  const float* b0[1]; const float* b1[1]; float sc0[1] = {1.f}, sc1[1] = {1.f};
  b0[0] = p.Ain + (size_t)(mBase + (t>>3)) * 512;
  b1[0] = b0[0] + (size_t)16 * 512;
  const int kofs = (t & 7)*4;
  const float* w0 = p.W + (size_t)(nBase + (t>>3)) * 512 + kofs;
  const float* w1 = w0 + (size_t)16 * 512;
  const float* w2 = w0 + (size_t)32 * 512;
  const float* w3 = w0 + (size_t)48 * 512;
  float acc[4][4] = {};
  gemm_loop<1, 1>(b0, b1, sc0, sc1, w0, w1, w2, w3, kBeg, kEnd, As, Bs, acc);
  const int tx = t & 15, ty = t >> 4;
#pragma unroll
  for (int i = 0; i < 4; i++) {
    int r = mBase + ty*4 + i;
    *(float4*)&p.pbuf[((size_t)z*64 + r)*512 + nBase + tx*4] =
      make_float4(acc[i][0],acc[i][1],acc[i][2],acc[i][3]);
  }
}

// epi for tiny layers: EPI 0 -> store; EPI 8 -> 14x tiled store
struct EPP {
  const float* pbuf; const float* bias;
  float* outp; int SK; float gain;
};
template<int EPI>
__global__ __launch_bounds__(256) void epi_k(EPP e) {
  int i = blockIdx.x*256 + threadIdx.x;
  if (i >= 64*128) return;
  int m = i >> 7, n4 = (i & 127) * 4;
  float ys[4] = {0.f, 0.f, 0.f, 0.f};
  for (int z = 0; z < e.SK; z++) {
    float4 v = *(const float4*)&e.pbuf[((size_t)z*64 + m)*512 + n4];
    ys[0] += v.x; ys[1] += v.y; ys[2] += v.z; ys[3] += v.w;
  }
#pragma unroll
  for (int j = 0; j < 4; j++) {
    float y = ys[j] * e.gain + e.bias[n4+j] * LRc;
    ys[j] = (y > 0.f ? y : 0.2f*y) * SQ2;
  }
  float4 ov = make_float4(ys[0], ys[1], ys[2], ys[3]);
  if (EPI == 0) {
    *(float4*)&e.outp[(size_t)m*512 + n4] = ov;
  } else { // 8
#pragma unroll
    for (int w = 0; w < 14; w++)
      *(float4*)&e.outp[((size_t)(m*14 + w))*512 + n4] = ov;
  }
}

// fused 3-table GEMM: Ts/Td/T0 partials, grid (2, 24, SK_T) (f32)
struct TABP { const float* zn; const float* We; const float* Wn;
              float* pbTs; float* pbTd; float* pbT0; };
__global__ __launch_bounds__(128) void tab_k(TABP q) {
  int wsel = blockIdx.y >> 3;
  int nBase = (blockIdx.y & 7) * 64;
  const float* W = (wsel == 2) ? q.Wn : q.We;
  int Wld = (wsel == 2) ? 1030 : 1034;
  int Woff = (wsel == 1) ? 515 : 0;
  float* pb = (wsel == 0) ? q.pbTs : (wsel == 1) ? q.pbTd : q.pbT0;
  int z = blockIdx.z;
  __shared__ float As[32][36];
  __shared__ float Bs[32][68];
  const int t = threadIdx.x;
  const int mBase = blockIdx.x * 32;
  const float* b0[1]; const float* b1[1]; float sc0[1] = {1.f}, sc1[1] = {1.f};
  b0[0] = q.zn + (size_t)(mBase + (t>>3)) * 512;
  b1[0] = b0[0] + 16*512;
  const int kofs = (t & 7)*4 + Woff;
  const float* w0 = W + (size_t)(nBase + (t>>3)) * Wld + kofs;
  const float* w1 = w0 + (size_t)16 * Wld;
  const float* w2 = w0 + (size_t)32 * Wld;
  const float* w3 = w0 + (size_t)48 * Wld;
  float acc[4][4] = {};
  gemm_loop<0, 1>(b0, b1, sc0, sc1, w0, w1, w2, w3, z*128, z*128+128, As, Bs, acc);
  const int tx = t & 15, ty = t >> 4;
#pragma unroll
  for (int i = 0; i < 4; i++) {
    int r = mBase + ty*4 + i;
    *(float4*)&pb[((size_t)z*64 + r)*512 + nBase + tx*4] =
      make_float4(acc[i][0],acc[i][1],acc[i][2],acc[i][3]);
  }
}

// ---- compaction helpers ----
__device__ __forceinline__ int blockCount(int pred, int* ws4) {
  unsigned long long m = __ballot(pred);
  int lane = threadIdx.x & 63, w = threadIdx.x >> 6;
  if (lane == 0) ws4[w] = __popcll(m);
  __syncthreads();
  return ws4[0] + ws4[1] + ws4[2] + ws4[3];
}
__device__ __forceinline__ int blockRank(int pred, int* ws4) {
  unsigned long long m = __ballot(pred);
  int lane = threadIdx.x & 63, w = threadIdx.x >> 6;
  if (lane == 0) ws4[w] = __popcll(m);
  __syncthreads();
  int off = 0;
  for (int i = 0; i < w; i++) off += ws4[i];
  return off + __popcll(m & ((1ull << lane) - 1ull));
}
__device__ __forceinline__ int blockSumN(const int* arr, int n, int* red) {
  int local = 0;
  for (int i = threadIdx.x; i < n; i += 256) local += arr[i];
  for (int o = 32; o > 0; o >>= 1) local += __shfl_down(local, o);
  if ((threadIdx.x & 63) == 0) red[threadIdx.x >> 6] = local;
  __syncthreads();
  int s = red[0]+red[1]+red[2]+red[3];
  __syncthreads();
  return s;
}

// mega init: rms | need %250 marks (1s only; zeros from memset) | W transposes |
//            ES scan: cnt atomics + need[src]=1 + bcntS   (all writes order-free)
__global__ __launch_bounds__(256) void init_k(const float* z, float* zn, int* need,
                                              const float* W0, const float* Wn,
                                              float* w0s, float* w0n,
                                              const int* src, const int* dst,
                                              float* cnt, int* bcnt) {
  __shared__ int ws4[4];
  int b = blockIdx.x, t = threadIdx.x;
  if (b < 64) {
    float s = 0.f;
    for (int j = t; j < 512; j += 256) { float v = z[b*512+j]; s += v*v; }
    for (int o = 32; o > 0; o >>= 1) s += __shfl_down(s, o);
    __shared__ float red[5];
    if ((t & 63) == 0) red[t >> 6] = s;
    __syncthreads();
    if (t == 0) {
      float tot = red[0]+red[1]+red[2]+red[3];
      red[4] = 1.0f / sqrtf(tot * (1.0f/512.0f) + 1e-8f);
    }
    __syncthreads();
    float r = red[4];
    for (int j = t; j < 512; j += 256) zn[b*512+j] = z[b*512+j] * r;
  } else if (b < 127) {
    int n = (b-64)*256 + t;
    if (n < NN && (n % NVP) == 0) need[n] = 1;
  } else if (b < 129) {
    int c = (b-127)*256 + t;
    const float* row = W0 + (size_t)c*1034;
    w0s[0*512+c] = row[512];  w0s[1*512+c] = row[513];  w0s[2*512+c] = row[514];
    w0s[3*512+c] = row[1027]; w0s[4*512+c] = row[1028]; w0s[5*512+c] = row[1029];
    w0s[6*512+c] = row[1030]; w0s[7*512+c] = row[1031]; w0s[8*512+c] = row[1032];
    w0s[9*512+c] = row[1033];
    const float* rn = Wn + (size_t)c*1030;
#pragma unroll
    for (int j = 0; j < 6; j++) w0n[j*512+c] = rn[512+j];
  } else {
    int bl = b - 129;
    int e = bl*256 + t;
    int pred = 0;
    if (e < EN) {
      int d = dst[e];
      atomicAdd(&cnt[d], 1.0f);   // integer-valued: exact, order-free
      pred = (d % NVP) == 0;
      if (pred) need[src[e]] = 1;
    }
    int c = blockCount(pred, ws4);
    if (t == 0) bcnt[bl] = c;
  }
}

__global__ __launch_bounds__(256) void cntE0N1_k(const int* dst, const int* need,
                                                 int* bcntE, int* bcntN) {
  __shared__ int ws4[4];
  int b = blockIdx.x;
  if (b < EBLK) {
    int e = b*256 + threadIdx.x;
    int pred = (e < EN) && need[dst[e]];
    int c = blockCount(pred, ws4);
    if (threadIdx.x == 0) bcntE[b] = c;
  } else {
    int n = (b-EBLK)*256 + threadIdx.x;
    int pred = (n < NN) && need[n];
    int c = blockCount(pred, ws4);
    if (threadIdx.x == 0) bcntN[b-EBLK] = c;
  }
}
__global__ __launch_bounds__(256) void emit3s_k(const int* src, const int* dst,
                                                const int* need,
                                                const int* bcntS, int* listES,
                                                const int* bcntE, int* listE0, int* posOf,
                                                const int* bcntN, int* listN1, int* posN,
                                                int* tot) {
  __shared__ int red[4];
  __shared__ int ws4[4];
  int b = blockIdx.x;
  const int* bcnt; int bl, nblk, seg;
  if (b < EBLK)        { seg = 0; bl = b;          bcnt = bcntS; nblk = EBLK; }
  else if (b < 2*EBLK) { seg = 1; bl = b - EBLK;   bcnt = bcntE; nblk = EBLK; }
  else                 { seg = 2; bl = b - 2*EBLK; bcnt = bcntN; nblk = NBLK; }
  int boff = blockSumN(bcnt, bl, red);
  if (bl == 0) {
    int tt = blockSumN(bcnt, nblk, red);
    if (threadIdx.x == 0) tot[seg] = tt;
  }
  if (seg == 0) {
    int e = bl*256 + threadIdx.x;
    int pred = (e < EN) && (dst[e] % NVP == 0);
    int rank = blockRank(pred, ws4);
    if (pred) { int pos = boff + rank; if (pos < CAP_ES) listES[pos] = e; }
  } else if (seg == 1) {
    int e = bl*256 + threadIdx.x;
    int pred = (e < EN) && need[dst[e]];
    int rank = blockRank(pred, ws4);
    if (pred) { int pos = boff + rank;
      if (pos < CAP_E0) { listE0[pos] = e; posOf[e] = pos; } }
  } else {
    int n = bl*256 + threadIdx.x;
    int pred = (n < NN) && need[n];
    int rank = blockRank(pred, ws4);
    if (pred) { int pos = boff + rank;
      if (pos < CAP_N1) { listN1[pos] = n; posN[n] = pos; } }
  }
}

// P0 edge L0 via Ts/Td partial tables, float4
__global__ __launch_bounds__(128) void edge0_k(const int* nE0p, const int* listE0,
                                               const int* src, const int* dst,
                                               const float* pbTs, const float* pbTd,
                                               const float* la, const float* w0s,
                                               const float* b0, float* h0c) {
  int i = blockIdx.x;
  int n0 = *nE0p; if (n0 > CAP_E0) n0 = CAP_E0;
  if (i >= n0) return;
  int tid = threadIdx.x;
  int e = listE0[i];
  int s = src[e], d = dst[e];
  float a0 = la[s*3], a1 = la[s*3+1], a2 = la[s*3+2];
  float c0 = la[d*3], c1 = la[d*3+1], c2 = la[d*3+2];
  float r0 = c0-a0, r1 = c1-a1, r2 = c2-a2;
  float dn = sqrtf(r0*r0 + r1*r1 + r2*r2);
  const float g = LRc / 32.1558704423f; // sqrt(1034)
  int sr = s & 63, dr = d & 63;
  int c4 = tid*4;
  float ys[4] = {0.f,0.f,0.f,0.f};
#pragma unroll
  for (int z = 0; z < SK_T; z++) {
    float4 vs = *(const float4*)&pbTs[((size_t)z*64 + sr)*512 + c4];
    float4 vd = *(const float4*)&pbTd[((size_t)z*64 + dr)*512 + c4];
    ys[0] += vs.x + vd.x; ys[1] += vs.y + vd.y;
    ys[2] += vs.z + vd.z; ys[3] += vs.w + vd.w;
  }
  float cf[10] = {a0,a1,a2,c0,c1,c2,r0,r1,r2,dn};
#pragma unroll
  for (int j = 0; j < 10; j++) {
    float4 wv = *(const float4*)&w0s[j*512 + c4];
    ys[0] += cf[j]*wv.x; ys[1] += cf[j]*wv.y; ys[2] += cf[j]*wv.z; ys[3] += cf[j]*wv.w;
  }
  float4 bv = *(const float4*)&b0[c4];
  float bb[4] = {bv.x, bv.y, bv.z, bv.w};
#pragma unroll
  for (int j = 0; j < 4; j++) {
    float y = ys[j]*g + bb[j]*LRc;
    ys[j] = (y > 0.f ? y : 0.2f*y) * SQ2;
  }
  *(float4*)&h0c[(size_t)i*512 + c4] = make_float4(ys[0],ys[1],ys[2],ys[3]);
}

extern "C" void kernel_launch(void* const* d_in, const int* in_sizes, int n_in,
                              void* d_out, int out_size, void* d_ws, size_t ws_size,
                              hipStream_t stream) {
  const float* z     = (const float*)d_in[0];
  const float* la    = (const float*)d_in[1];
  const int*   ei    = (const int*)  d_in[2];
  const float* p0ew0 = (const float*)d_in[3];
  const float* p0eb0 = (const float*)d_in[4];
  const float* p0ew1 = (const float*)d_in[5];
  const float* p0eb1 = (const float*)d_in[6];
  const float* p0nw0 = (const float*)d_in[7];
  const float* p0nb0 = (const float*)d_in[8];
  const float* p0nw1 = (const float*)d_in[9];
  const float* p0nb1 = (const float*)d_in[10];
  const float* p1ew0 = (const float*)d_in[11];
  const float* p1eb0 = (const float*)d_in[12];
  const float* p1ew1 = (const float*)d_in[13];
  const float* p1eb1 = (const float*)d_in[14];
  const float* p1nw0 = (const float*)d_in[15];
  const float* p1nb0 = (const float*)d_in[16];
  const float* p1nw1 = (const float*)d_in[17];
  const float* p1nb1 = (const float*)d_in[18];
  const int* src = ei;
  const int* dst = ei + EN;

  char* ws = (char*)d_ws;
  size_t off = 0;
  auto al = [&](size_t bytes) -> void* {
    void* r = (void*)(ws + off);
    off += (bytes + 255) & ~(size_t)255;
    return r;
  };
  // ---- zeroed region: atomic targets + need (1s-only writers) ----
  float* cnt    = (float*)al(NN*4);
  int*   need   = (int*)  al(NN*4);
  float* agg0c  = (float*)al((size_t)CAP_N1*512*4);
  float* agg1c  = (float*)al(64*512*4);
  size_t zEnd = off;
  // ---- written-before-read region ----
  int*   tot    = (int*)  al(3*4);
  int*   posN   = (int*)  al(NN*4);
  int*   posOf  = (int*)  al((size_t)EN*4);
  int*   bcntS  = (int*)  al(EBLK*4);
  int*   bcntE  = (int*)  al(EBLK*4);
  int*   bcntN  = (int*)  al(NBLK*4);
  int*   listES = (int*)  al(CAP_ES*4);
  int*   listN1 = (int*)  al(CAP_N1*4);
  int*   listE0 = (int*)  al(CAP_E0*4);
  float* zn     = (float*)al(64*512*4);
  float* w0s    = (float*)al(10*512*4);
  float* w0n    = (float*)al(6*512*4);
  float* pbTs   = (float*)al((size_t)SK_T*64*512*4);
  float* pbTd   = (float*)al((size_t)SK_T*64*512*4);
  float* pbT0   = (float*)al((size_t)SK_T*64*512*4);
  float* h0c    = (float*)al((size_t)CAP_E0*512*4);
  float* ef0c   = (float*)al((size_t)CAP_E0*512*4);
  float* hn1    = (float*)al((size_t)CAP_N1*512*4);
  float* x1c    = (float*)al((size_t)CAP_N1*512*4);
  float* hs     = (float*)al((size_t)CAP_ES*512*4);
  float* hn64   = (float*)al(64*512*4);
  float* pbuf   = (float*)al((size_t)SK_GS*CAP_ES*512*4);  // 25 MB (gemmGS SK=12; tails reuse)

  hipMemsetAsync(ws, 0, zEnd, stream);

  init_k<<<129 + EBLK, 256, 0, stream>>>(z, zn, need, p0ew0, p0nw0, w0s, w0n,
                                         src, dst, cnt, bcntS);
  cntE0N1_k<<<EBLK+NBLK, 256, 0, stream>>>(dst, need, bcntE, bcntN);
  emit3s_k<<<2*EBLK+NBLK, 256, 0, stream>>>(src, dst, need, bcntS, listES,
                                            bcntE, listE0, posOf,
                                            bcntN, listN1, posN, tot);
  {
    TABP q{zn, p0ew0, p0nw0, pbTs, pbTd, pbT0};
    tab_k<<<dim3(2, 24, SK_T), 128, 0, stream>>>(q);
  }
  edge0_k<<<CAP_E0, 128, 0, stream>>>(tot+1, listE0, src, dst, pbTs, pbTd, la, w0s,
                                      p0eb0, h0c);

  // P0 edge L1 (MFMA fused EPI1): K=512 -> ef0c + atomic agg0c
  {
    GMF p{}; p.W = p0ew1; p.Wld = 512; p.Woff = 0; p.Astride = 512;
    p.K = 512; p.Mcap = CAP_E0; p.Mdev = tot+1; p.Ain = h0c;
    p.f.bias = p0eb1; p.f.gain = LRc/sqrtf(512.f);
    p.f.rmap = listE0; p.f.dst = dst; p.f.posN = posN;
    p.f.outp = ef0c; p.f.atomp = agg0c;
    gemmMF<1,0,1><<<dim3(CAP_E0/64, 8), 256, 0, stream>>>(p);
  }
  // P0 node L0 (MFMA fused EPI7, row-scaled, scalar-W): K=512 over agg0c -> hn1
  {
    GMF p{}; p.W = p0nw0; p.Wld = 1030; p.Woff = 518; p.Astride = 512;
    p.K = 512; p.Mcap = CAP_N1; p.Mdev = tot+2;
    p.Ain = agg0c; p.cnt = cnt; p.listN1 = listN1;
    p.f.bias = p0nb0; p.f.gain = LRc/sqrtf(1030.f);
    p.f.T0p = pbT0; p.f.la = la; p.f.cnt = cnt; p.f.w0n = w0n; p.f.rmap = listN1;
    p.f.outp = hn1;
    gemmMF<0,1,7><<<dim3(CAP_N1/64, 8), 256, 0, stream>>>(p);
  }
  // P0 node L1 (MFMA fused EPI0) -> x1c
  {
    GMF p{}; p.W = p0nw1; p.Wld = 512; p.Woff = 0; p.Astride = 512;
    p.K = 512; p.Mcap = CAP_N1; p.Mdev = tot+2; p.Ain = hn1;
    p.f.bias = p0nb1; p.f.gain = LRc/sqrtf(512.f); p.f.outp = x1c;
    gemmMF<1,0,0><<<dim3(CAP_N1/64, 8), 256, 0, stream>>>(p);
  }
  // P1 edge L0 (MFMA gather, split-K SK=12): K=1536 -> pbuf -> hs
  {
    GGS p{}; p.W = p1ew0; p.x1c = x1c; p.ef0c = ef0c;
    p.listES = listES; p.src = src; p.dst = dst; p.posN = posN; p.posOf = posOf;
    p.Mdev = tot+0; p.pbuf = pbuf; p.KC = 128;
    gemmGS<<<dim3(CAP_ES/64, 8, SK_GS), 256, 0, stream>>>(p);
    EPS e{}; e.pbuf = pbuf; e.SK = SK_GS; e.Mdev = tot+0;
    e.bias = p1eb0; e.gain = LRc/sqrtf(1536.f); e.outp = hs;
    epiS_k<<<(CAP_ES*128)/256, 256, 0, stream>>>(e);
  }
  // P1 edge L1 (MFMA fused EPI2): K=512 -> atomic agg1c
  {
    GMF p{}; p.W = p1ew1; p.Wld = 512; p.Woff = 0; p.Astride = 512;
    p.K = 512; p.Mcap = CAP_ES; p.Mdev = tot+0; p.Ain = hs;
    p.f.bias = p1eb1; p.f.gain = LRc/sqrtf(512.f);
    p.f.rmap = listES; p.f.dst = dst; p.f.atomp = agg1c;
    gemmMF<1,0,2><<<dim3(CAP_ES/64, 8), 256, 0, stream>>>(p);
  }
  // P1 node L0 (f32 split-K SK=8): K=1024 -> pbuf -> hn64
  {
    GTP p{}; p.W = p1nw0; p.x1c = x1c; p.agg1c = agg1c; p.cnt = cnt;
    p.posN = posN; p.pbuf = pbuf; p.KC = 128;
    gemmT<<<dim3(2, 8, 8), 128, 0, stream>>>(p);
    EPP e{}; e.pbuf = pbuf; e.SK = 8; e.bias = p1nb0;
    e.gain = LRc/sqrtf(1024.f); e.outp = hn64;
    epi_k<0><<<(64*128)/256, 256, 0, stream>>>(e);
  }
  // P1 node L1 (f32 split-K SK=4): K=512 -> pbuf -> d_out (14x tiled)
  {
    GPP p{}; p.W = p1nw1; p.Ain = hn64; p.pbuf = pbuf; p.KC = 128;
    gemmP<<<dim3(2, 8, 4), 128, 0, stream>>>(p);
    EPP e{}; e.pbuf = pbuf; e.SK = 4; e.bias = p1nb1;
    e.gain = LRc/sqrtf(512.f); e.outp = (float*)d_out;
    epi_k<8><<<(64*128)/256, 256, 0, stream>>>(e);
  }
}

// Round 18
// 134.409 us; speedup vs baseline: 1.0307x; 1.0307x over previous
//
#include <hip/hip_runtime.h>
#include <hip/hip_bf16.h>
#include <cmath>

#define NVP 250
#define NN  16000
#define EN  95232
#define LRc 0.01f
#define SQ2 1.41421356237309515f

#define CAP_ES 1024
#define CAP_N1 1024
#define CAP_E0 4096
#define EBLK ((EN + 255) / 256)   // 372
#define NBLK ((NN + 255) / 256)   // 63
#define SK_T 4
#define SK_GS 6

typedef __attribute__((ext_vector_type(8))) short bf16x8;
typedef __attribute__((ext_vector_type(4))) float f32x4;

__device__ __forceinline__ unsigned short bfc(float x) {
  unsigned u = __builtin_bit_cast(unsigned, x);
  u = (u + 0x7fffu + ((u >> 16) & 1u)) >> 16;   // RNE
  return (unsigned short)u;
}
__device__ __forceinline__ unsigned pk2(float a, float b) {
  return (unsigned)bfc(a) | ((unsigned)bfc(b) << 16);
}

// ---------------- fused epilogue params ----------------
struct FEP {
  const float* bias; float gain;
  const float* T0p; const float* la; const float* cnt; const float* w0n;  // EPI7
  const int* rmap; const int* dst; const int* posN;                        // EPI1/2/7
  float* outp; float* atomp;
};

// EPI 0: store outp. EPI 1: store + atomicAdd agg0c[posN[dst[rmap]]].
// EPI 2: atomicAdd agg1c[dst[rmap]/250]. EPI 7: +T0 +la*w0n, store.
template<int EPI>
__device__ __forceinline__ void mfma_epi(const FEP& f, f32x4 acc0, f32x4 acc1,
                                         f32x4 acc2, f32x4 acc3,
                                         int mBase, int nBase, int M,
                                         int lane, int wv) {
  const int fcol = lane & 15;
  int rows[4]; bool rok[4]; int tr[4];
  int rr4[4]; float la0[4], la1[4], la2[4]; bool has[4];
#pragma unroll
  for (int r = 0; r < 4; r++) {
    int row = mBase + wv*16 + (lane >> 4)*4 + r;
    rows[r] = row; rok[r] = row < M;
    int rc = rok[r] ? row : 0;
    if (EPI == 1) tr[r] = f.posN[f.dst[f.rmap[rc]]];
    if (EPI == 2) tr[r] = f.dst[f.rmap[rc]] / NVP;
    if (EPI == 7) {
      int nd = f.rmap[rc];
      rr4[r] = nd & 63;
      la0[r] = f.la[nd*3]; la1[r] = f.la[nd*3+1]; la2[r] = f.la[nd*3+2];
      has[r] = f.cnt[nd] > 0.f;
    }
  }
  f32x4 accs[4] = {acc0, acc1, acc2, acc3};
#pragma unroll
  for (int c = 0; c < 4; c++) {
    int n = nBase + fcol + 16*c;
    float bi = f.bias[n] * LRc;
    float w6[6];
    if (EPI == 7) {
#pragma unroll
      for (int j = 0; j < 6; j++) w6[j] = f.w0n[j*512 + n];
    }
#pragma unroll
    for (int r = 0; r < 4; r++) {
      if (!rok[r]) continue;
      float yr = accs[c][r];
      if (EPI == 7) {
#pragma unroll
        for (int zz = 0; zz < SK_T; zz++)
          yr += f.T0p[((size_t)zz*64 + rr4[r])*512 + n];
        float corr = la0[r]*w6[0] + la1[r]*w6[1] + la2[r]*w6[2];
        if (has[r]) corr += la0[r]*w6[3] + la1[r]*w6[4] + la2[r]*w6[5];
        yr += corr;
      }
      float y = yr * f.gain + bi;
      y = (y > 0.f ? y : 0.2f*y) * SQ2;
      if (EPI == 0 || EPI == 7) {
        f.outp[(size_t)rows[r]*512 + n] = y;
      } else if (EPI == 1) {
        f.outp[(size_t)rows[r]*512 + n] = y;
        atomicAdd(&f.atomp[(size_t)tr[r]*512 + n], y);
      } else { // 2
        atomicAdd(&f.atomp[(size_t)tr[r]*512 + n], y);
      }
    }
  }
}

// ---------------- LDS-staged bf16 MFMA GEMM, SK=1, fused epilogue ----------------
struct GMF {
  const float* W; const float* Ain; const int* Mdev;
  const float* cnt; const int* listN1;
  int Wld, Woff, Astride, K, Mcap, Mfix;
  FEP f;
};

template<int VECW, int SCALED, int EPI>
__global__ __launch_bounds__(256) void gemmMF(GMF p) {
  int M = p.Mdev ? *p.Mdev : p.Mfix;
  if (M > p.Mcap) M = p.Mcap;
  const int mBase = blockIdx.x * 64;
  if (mBase >= M) return;
  const int nBase = blockIdx.y * 64;

  __shared__ unsigned short Abf[64*72];
  __shared__ unsigned short Wbf[64*72];
  const int t = threadIdx.x;
  const int srow = t >> 2, sq = (t & 3) * 16;
  int arow = mBase + srow; if (arow >= M) arow = M - 1;
  float s = 1.f;
  if (SCALED) s = 1.0f / fmaxf(p.cnt[p.listN1[arow]], 1.0f);
  const float* aRow = p.Ain + (size_t)arow * p.Astride + sq;
  const float* wRow = p.W + (size_t)(nBase + srow) * p.Wld + p.Woff + sq;

  float4 ra[4], rw[4];
  auto ld = [&](int kt) {
#pragma unroll
    for (int i = 0; i < 4; i++) {
      ra[i] = *(const float4*)(aRow + kt + 4*i);
      if (VECW) {
        rw[i] = *(const float4*)(wRow + kt + 4*i);
      } else {
        const float* wp = wRow + kt + 4*i;
        rw[i] = make_float4(wp[0], wp[1], wp[2], wp[3]);
      }
    }
  };
  ld(0);

  const int lane = t & 63, wv = t >> 6;
  const int fr = wv*16 + (lane & 15);
  const int fcol = (lane & 15);
  const int fo = (lane >> 4) * 8;
  f32x4 acc0 = {}, acc1 = {}, acc2 = {}, acc3 = {};

  for (int kt = 0; kt < p.K; kt += 64) {
    if (kt > 0) __syncthreads();
    unsigned short* da = &Abf[srow*72 + sq];
    unsigned short* dw = &Wbf[srow*72 + sq];
#pragma unroll
    for (int i = 0; i < 4; i++) {
      uint2 ua; ua.x = pk2(ra[i].x*s, ra[i].y*s); ua.y = pk2(ra[i].z*s, ra[i].w*s);
      *(uint2*)&da[i*4] = ua;
      uint2 uw; uw.x = pk2(rw[i].x, rw[i].y); uw.y = pk2(rw[i].z, rw[i].w);
      *(uint2*)&dw[i*4] = uw;
    }
    __syncthreads();
    if (kt + 64 < p.K) ld(kt + 64);
#pragma unroll
    for (int kk = 0; kk < 64; kk += 32) {
      bf16x8 a = *(const bf16x8*)&Abf[fr*72 + kk + fo];
      bf16x8 b0 = *(const bf16x8*)&Wbf[( 0 + fcol)*72 + kk + fo];
      bf16x8 b1 = *(const bf16x8*)&Wbf[(16 + fcol)*72 + kk + fo];
      bf16x8 b2 = *(const bf16x8*)&Wbf[(32 + fcol)*72 + kk + fo];
      bf16x8 b3 = *(const bf16x8*)&Wbf[(48 + fcol)*72 + kk + fo];
      acc0 = __builtin_amdgcn_mfma_f32_16x16x32_bf16(a, b0, acc0, 0, 0, 0);
      acc1 = __builtin_amdgcn_mfma_f32_16x16x32_bf16(a, b1, acc1, 0, 0, 0);
      acc2 = __builtin_amdgcn_mfma_f32_16x16x32_bf16(a, b2, acc2, 0, 0, 0);
      acc3 = __builtin_amdgcn_mfma_f32_16x16x32_bf16(a, b3, acc3, 0, 0, 0);
    }
  }
  mfma_epi<EPI>(p.f, acc0, acc1, acc2, acc3, mBase, nBase, M, lane, wv);
}

// P1 edge L0, split-K MFMA gather: A row = [x1c[posN[src]]|x1c[posN[dst]]|ef0c[posOf]]
struct GGS {
  const float* W; const float* x1c; const float* ef0c;
  const int* listES; const int* src; const int* dst; const int* posN; const int* posOf;
  const int* Mdev; float* pbuf; int KC;
};
__global__ __launch_bounds__(256) void gemmGS(GGS p) {
  int M = *p.Mdev; if (M > CAP_ES) M = CAP_ES;
  const int mBase = blockIdx.x * 64;
  if (mBase >= M) return;
  const int nBase = blockIdx.y * 64;
  const int z = blockIdx.z;
  int kBeg = z * p.KC, kEnd = kBeg + p.KC;

  __shared__ unsigned short Abf[64*72];
  __shared__ unsigned short Wbf[64*72];
  const int t = threadIdx.x;
  const int srow = t >> 2, sq = (t & 3) * 16;
  int arow = mBase + srow; if (arow >= M) arow = M - 1;
  int e = p.listES[arow];
  const float* s0 = p.x1c + (size_t)p.posN[p.src[e]] * 512;
  const float* s1 = p.x1c + (size_t)p.posN[p.dst[e]] * 512;
  const float* s2 = p.ef0c + (size_t)p.posOf[e] * 512;
  const float* wRow = p.W + (size_t)(nBase + srow) * 1536 + sq;

  float4 ra[4], rw[4];
  auto ld = [&](int kt) {
    int ka = kt + sq;
    const float* ap = (ka < 512) ? (s0 + ka) : (ka < 1024) ? (s1 + ka - 512)
                                                           : (s2 + ka - 1024);
#pragma unroll
    for (int i = 0; i < 4; i++) {
      ra[i] = *(const float4*)(ap + 4*i);
      rw[i] = *(const float4*)(wRow + kt + 4*i);
    }
  };
  ld(kBeg);

  const int lane = t & 63, wv = t >> 6;
  const int fr = wv*16 + (lane & 15);
  const int fcol = (lane & 15);
  const int fo = (lane >> 4) * 8;
  f32x4 acc0 = {}, acc1 = {}, acc2 = {}, acc3 = {};

  for (int kt = kBeg; kt < kEnd; kt += 64) {
    if (kt > kBeg) __syncthreads();
    unsigned short* da = &Abf[srow*72 + sq];
    unsigned short* dw = &Wbf[srow*72 + sq];
#pragma unroll
    for (int i = 0; i < 4; i++) {
      uint2 ua; ua.x = pk2(ra[i].x, ra[i].y); ua.y = pk2(ra[i].z, ra[i].w);
      *(uint2*)&da[i*4] = ua;
      uint2 uw; uw.x = pk2(rw[i].x, rw[i].y); uw.y = pk2(rw[i].z, rw[i].w);
      *(uint2*)&dw[i*4] = uw;
    }
    __syncthreads();
    if (kt + 64 < kEnd) ld(kt + 64);
#pragma unroll
    for (int kk = 0; kk < 64; kk += 32) {
      bf16x8 a = *(const bf16x8*)&Abf[fr*72 + kk + fo];
      bf16x8 b0 = *(const bf16x8*)&Wbf[( 0 + fcol)*72 + kk + fo];
      bf16x8 b1 = *(const bf16x8*)&Wbf[(16 + fcol)*72 + kk + fo];
      bf16x8 b2 = *(const bf16x8*)&Wbf[(32 + fcol)*72 + kk + fo];
      bf16x8 b3 = *(const bf16x8*)&Wbf[(48 + fcol)*72 + kk + fo];
      acc0 = __builtin_amdgcn_mfma_f32_16x16x32_bf16(a, b0, acc0, 0, 0, 0);
      acc1 = __builtin_amdgcn_mfma_f32_16x16x32_bf16(a, b1, acc1, 0, 0, 0);
      acc2 = __builtin_amdgcn_mfma_f32_16x16x32_bf16(a, b2, acc2, 0, 0, 0);
      acc3 = __builtin_amdgcn_mfma_f32_16x16x32_bf16(a, b3, acc3, 0, 0, 0);
    }
  }
  float* ob = p.pbuf + (size_t)z * CAP_ES * 512;
  int orow = mBase + wv*16 + (lane >> 4) * 4;
  int oc = nBase + fcol;
#pragma unroll
  for (int r = 0; r < 4; r++) {
    float* q = ob + (size_t)(orow + r) * 512 + oc;
    q[0] = acc0[r]; q[16] = acc1[r]; q[32] = acc2[r]; q[48] = acc3[r];
  }
}

// epilogue for gemmGS: runtime-M, sum SK partials, activation, store hs
struct EPS {
  const float* pbuf; const float* bias; const int* Mdev;
  float* outp; int SK; float gain;
};
__global__ __launch_bounds__(256) void epiS_k(EPS e) {
  int M = *e.Mdev; if (M > CAP_ES) M = CAP_ES;
  int i = blockIdx.x*256 + threadIdx.x;
  if (i >= M*128) return;
  int m = i >> 7, n4 = (i & 127) * 4;
  float ys[4] = {0.f, 0.f, 0.f, 0.f};
  for (int z = 0; z < e.SK; z++) {
    float4 v = *(const float4*)&e.pbuf[((size_t)z*CAP_ES + m)*512 + n4];
    ys[0] += v.x; ys[1] += v.y; ys[2] += v.z; ys[3] += v.w;
  }
#pragma unroll
  for (int j = 0; j < 4; j++) {
    float y = ys[j] * e.gain + e.bias[n4+j] * LRc;
    ys[j] = (y > 0.f ? y : 0.2f*y) * SQ2;
  }
  *(float4*)&e.outp[(size_t)m*512 + n4] = make_float4(ys[0],ys[1],ys[2],ys[3]);
}

// ---------------- f32 pipelined GEMM loop ----------------
template<int VECW, int NSEG>
__device__ __forceinline__ void gemm_loop(
    const float* const* b0, const float* const* b1,
    const float* sc0, const float* sc1,
    const float* w0, const float* w1, const float* w2, const float* w3,
    int kBeg, int kEnd,
    float (*As)[36], float (*Bs)[68], float acc[4][4]) {
  const int t = threadIdx.x;
  const int k4 = (t & 7) * 4;
  const int mr = t >> 3;
  const int tx = t & 15, ty = t >> 4;
  float4 ra0, ra1, rw0, rw1, rw2, rw3;
  auto lA = [&](int k0) {
    int ka = k0 + k4;
    int idx = 0;
    if (NSEG >= 2 && ka >= 512) idx = 1;
    if (NSEG == 3 && ka >= 1024) idx = 2;
    float s0 = sc0[idx], s1 = sc1[idx];
    ra0 = *(const float4*)(b0[idx] + ka);
    ra1 = *(const float4*)(b1[idx] + ka);
    ra0.x *= s0; ra0.y *= s0; ra0.z *= s0; ra0.w *= s0;
    ra1.x *= s1; ra1.y *= s1; ra1.z *= s1; ra1.w *= s1;
  };
  auto lW = [&](int k0) {
    if (VECW) {
      rw0 = *(const float4*)(w0 + k0); rw1 = *(const float4*)(w1 + k0);
      rw2 = *(const float4*)(w2 + k0); rw3 = *(const float4*)(w3 + k0);
    } else {
      rw0 = make_float4(w0[k0], w0[k0+1], w0[k0+2], w0[k0+3]);
      rw1 = make_float4(w1[k0], w1[k0+1], w1[k0+2], w1[k0+3]);
      rw2 = make_float4(w2[k0], w2[k0+1], w2[k0+2], w2[k0+3]);
      rw3 = make_float4(w3[k0], w3[k0+1], w3[k0+2], w3[k0+3]);
    }
  };
  lA(kBeg); lW(kBeg);
  for (int k0 = kBeg; k0 < kEnd; k0 += 32) {
    if (k0 > kBeg) __syncthreads();
    As[k4+0][mr] = ra0.x; As[k4+1][mr] = ra0.y;
    As[k4+2][mr] = ra0.z; As[k4+3][mr] = ra0.w;
    As[k4+0][mr+16] = ra1.x; As[k4+1][mr+16] = ra1.y;
    As[k4+2][mr+16] = ra1.z; As[k4+3][mr+16] = ra1.w;
    Bs[k4+0][mr]    = rw0.x; Bs[k4+1][mr]    = rw0.y; Bs[k4+2][mr]    = rw0.z; Bs[k4+3][mr]    = rw0.w;
    Bs[k4+0][mr+16] = rw1.x; Bs[k4+1][mr+16] = rw1.y; Bs[k4+2][mr+16] = rw1.z; Bs[k4+3][mr+16] = rw1.w;
    Bs[k4+0][mr+32] = rw2.x; Bs[k4+1][mr+32] = rw2.y; Bs[k4+2][mr+32] = rw2.z; Bs[k4+3][mr+32] = rw2.w;
    Bs[k4+0][mr+48] = rw3.x; Bs[k4+1][mr+48] = rw3.y; Bs[k4+2][mr+48] = rw3.z; Bs[k4+3][mr+48] = rw3.w;
    __syncthreads();
    if (k0 + 32 < kEnd) { lA(k0 + 32); lW(k0 + 32); }
#pragma unroll
    for (int kk = 0; kk < 32; kk++) {
      float4 a4 = *(const float4*)&As[kk][ty*4];
      float4 b4 = *(const float4*)&Bs[kk][tx*4];
      float aa[4] = {a4.x, a4.y, a4.z, a4.w};
      float bb[4] = {b4.x, b4.y, b4.z, b4.w};
#pragma unroll
      for (int i = 0; i < 4; i++)
#pragma unroll
        for (int j = 0; j < 4; j++) acc[i][j] += aa[i]*bb[j];
    }
  }
}

// P1 node L0 (M=64, f32, split-K)
struct GTP {
  const float* W; const float* x1c; const float* agg1c; const float* cnt;
  const int* posN; float* pbuf; int KC;
};
__global__ __launch_bounds__(128) void gemmT(GTP p) {
  const int mBase = blockIdx.x * 32;
  const int nBase = blockIdx.y * 64;
  const int z = blockIdx.z;
  int kBeg = z * p.KC, kEnd = kBeg + p.KC;
  __shared__ float As[32][36];
  __shared__ float Bs[32][68];
  const int t = threadIdx.x;
  int r0 = mBase + (t>>3), r1 = r0 + 16;
  const float* b0[2] = { p.x1c + (size_t)p.posN[r0*NVP]*512,
                         p.agg1c + (size_t)r0*512 - 512 };
  const float* b1[2] = { p.x1c + (size_t)p.posN[r1*NVP]*512,
                         p.agg1c + (size_t)r1*512 - 512 };
  float sc0[2] = {1.f, 1.0f / fmaxf(p.cnt[r0*NVP], 1.0f)};
  float sc1[2] = {1.f, 1.0f / fmaxf(p.cnt[r1*NVP], 1.0f)};
  const int kofs = (t & 7)*4;
  const float* w0 = p.W + (size_t)(nBase + (t>>3)) * 1024 + kofs;
  const float* w1 = w0 + (size_t)16 * 1024;
  const float* w2 = w0 + (size_t)32 * 1024;
  const float* w3 = w0 + (size_t)48 * 1024;
  float acc[4][4] = {};
  gemm_loop<1, 2>(b0, b1, sc0, sc1, w0, w1, w2, w3, kBeg, kEnd, As, Bs, acc);
  const int tx = t & 15, ty = t >> 4;
#pragma unroll
  for (int i = 0; i < 4; i++) {
    int r = mBase + ty*4 + i;
    *(float4*)&p.pbuf[((size_t)z*64 + r)*512 + nBase + tx*4] =
      make_float4(acc[i][0],acc[i][1],acc[i][2],acc[i][3]);
  }
}

// P1 node L1 (M=64, f32, split-K)
struct GPP {
  const float* W; const float* Ain; float* pbuf; int KC;
};
__global__ __launch_bounds__(128) void gemmP(GPP p) {
  const int mBase = blockIdx.x * 32;
  const int nBase = blockIdx.y * 64;
  const int z = blockIdx.z;
  int kBeg = z * p.KC, kEnd = kBeg + p.KC;
  __shared__ float As[32][36];
  __shared__ float Bs[32][68];
  const int t = threadIdx.x;
  const float* b0[1]; const float* b1[1]; float sc0[1] = {1.f}, sc1[1] = {1.f};
  b0[0] = p.Ain + (size_t)(mBase + (t>>3)) * 512;
  b1[0] = b0[0] + (size_t)16 * 512;
  const int kofs = (t & 7)*4;
  const float* w0 = p.W + (size_t)(nBase + (t>>3)) * 512 + kofs;
  const float* w1 = w0 + (size_t)16 * 512;
  const float* w2 = w0 + (size_t)32 * 512;
  const float* w3 = w0 + (size_t)48 * 512;
  float acc[4][4] = {};
  gemm_loop<1, 1>(b0, b1, sc0, sc1, w0, w1, w2, w3, kBeg, kEnd, As, Bs, acc);
  const int tx = t & 15, ty = t >> 4;
#pragma unroll
  for (int i = 0; i < 4; i++) {
    int r = mBase + ty*4 + i;
    *(float4*)&p.pbuf[((size_t)z*64 + r)*512 + nBase + tx*4] =
      make_float4(acc[i][0],acc[i][1],acc[i][2],acc[i][3]);
  }
}

// epi for tiny layers: EPI 0 -> store; EPI 8 -> 14x tiled store
struct EPP {
  const float* pbuf; const float* bias;
  float* outp; int SK; float gain;
};
template<int EPI>
__global__ __launch_bounds__(256) void epi_k(EPP e) {
  int i = blockIdx.x*256 + threadIdx.x;
  if (i >= 64*128) return;
  int m = i >> 7, n4 = (i & 127) * 4;
  float ys[4] = {0.f, 0.f, 0.f, 0.f};
  for (int z = 0; z < e.SK; z++) {
    float4 v = *(const float4*)&e.pbuf[((size_t)z*64 + m)*512 + n4];
    ys[0] += v.x; ys[1] += v.y; ys[2] += v.z; ys[3] += v.w;
  }
#pragma unroll
  for (int j = 0; j < 4; j++) {
    float y = ys[j] * e.gain + e.bias[n4+j] * LRc;
    ys[j] = (y > 0.f ? y : 0.2f*y) * SQ2;
  }
  float4 ov = make_float4(ys[0], ys[1], ys[2], ys[3]);
  if (EPI == 0) {
    *(float4*)&e.outp[(size_t)m*512 + n4] = ov;
  } else { // 8
#pragma unroll
    for (int w = 0; w < 14; w++)
      *(float4*)&e.outp[((size_t)(m*14 + w))*512 + n4] = ov;
  }
}

// fused 3-table GEMM: Ts/Td/T0 partials, grid (2, 24, SK_T) (f32)
struct TABP { const float* zn; const float* We; const float* Wn;
              float* pbTs; float* pbTd; float* pbT0; };
__global__ __launch_bounds__(128) void tab_k(TABP q) {
  int wsel = blockIdx.y >> 3;
  int nBase = (blockIdx.y & 7) * 64;
  const float* W = (wsel == 2) ? q.Wn : q.We;
  int Wld = (wsel == 2) ? 1030 : 1034;
  int Woff = (wsel == 1) ? 515 : 0;
  float* pb = (wsel == 0) ? q.pbTs : (wsel == 1) ? q.pbTd : q.pbT0;
  int z = blockIdx.z;
  __shared__ float As[32][36];
  __shared__ float Bs[32][68];
  const int t = threadIdx.x;
  const int mBase = blockIdx.x * 32;
  const float* b0[1]; const float* b1[1]; float sc0[1] = {1.f}, sc1[1] = {1.f};
  b0[0] = q.zn + (size_t)(mBase + (t>>3)) * 512;
  b1[0] = b0[0] + 16*512;
  const int kofs = (t & 7)*4 + Woff;
  const float* w0 = W + (size_t)(nBase + (t>>3)) * Wld + kofs;
  const float* w1 = w0 + (size_t)16 * Wld;
  const float* w2 = w0 + (size_t)32 * Wld;
  const float* w3 = w0 + (size_t)48 * Wld;
  float acc[4][4] = {};
  gemm_loop<0, 1>(b0, b1, sc0, sc1, w0, w1, w2, w3, z*128, z*128+128, As, Bs, acc);
  const int tx = t & 15, ty = t >> 4;
#pragma unroll
  for (int i = 0; i < 4; i++) {
    int r = mBase + ty*4 + i;
    *(float4*)&pb[((size_t)z*64 + r)*512 + nBase + tx*4] =
      make_float4(acc[i][0],acc[i][1],acc[i][2],acc[i][3]);
  }
}

// ---- compaction helpers ----
__device__ __forceinline__ int blockCount(int pred, int* ws4) {
  unsigned long long m = __ballot(pred);
  int lane = threadIdx.x & 63, w = threadIdx.x >> 6;
  if (lane == 0) ws4[w] = __popcll(m);
  __syncthreads();
  return ws4[0] + ws4[1] + ws4[2] + ws4[3];
}
__device__ __forceinline__ int blockRank(int pred, int* ws4) {
  unsigned long long m = __ballot(pred);
  int lane = threadIdx.x & 63, w = threadIdx.x >> 6;
  if (lane == 0) ws4[w] = __popcll(m);
  __syncthreads();
  int off = 0;
  for (int i = 0; i < w; i++) off += ws4[i];
  return off + __popcll(m & ((1ull << lane) - 1ull));
}
__device__ __forceinline__ int blockSumN(const int* arr, int n, int* red) {
  int local = 0;
  for (int i = threadIdx.x; i < n; i += 256) local += arr[i];
  for (int o = 32; o > 0; o >>= 1) local += __shfl_down(local, o);
  if ((threadIdx.x & 63) == 0) red[threadIdx.x >> 6] = local;
  __syncthreads();
  int s = red[0]+red[1]+red[2]+red[3];
  __syncthreads();
  return s;
}

// mega init: rms | need %250 marks (1s only; zeros from memset) | W transposes |
//            ES scan: cnt atomics + need[src]=1 + bcntS   (all writes order-free)
__global__ __launch_bounds__(256) void init_k(const float* z, float* zn, int* need,
                                              const float* W0, const float* Wn,
                                              float* w0s, float* w0n,
                                              const int* src, const int* dst,
                                              float* cnt, int* bcnt) {
  __shared__ int ws4[4];
  int b = blockIdx.x, t = threadIdx.x;
  if (b < 64) {
    float s = 0.f;
    for (int j = t; j < 512; j += 256) { float v = z[b*512+j]; s += v*v; }
    for (int o = 32; o > 0; o >>= 1) s += __shfl_down(s, o);
    __shared__ float red[5];
    if ((t & 63) == 0) red[t >> 6] = s;
    __syncthreads();
    if (t == 0) {
      float tot = red[0]+red[1]+red[2]+red[3];
      red[4] = 1.0f / sqrtf(tot * (1.0f/512.0f) + 1e-8f);
    }
    __syncthreads();
    float r = red[4];
    for (int j = t; j < 512; j += 256) zn[b*512+j] = z[b*512+j] * r;
  } else if (b < 127) {
    int n = (b-64)*256 + t;
    if (n < NN && (n % NVP) == 0) need[n] = 1;
  } else if (b < 129) {
    int c = (b-127)*256 + t;
    const float* row = W0 + (size_t)c*1034;
    w0s[0*512+c] = row[512];  w0s[1*512+c] = row[513];  w0s[2*512+c] = row[514];
    w0s[3*512+c] = row[1027]; w0s[4*512+c] = row[1028]; w0s[5*512+c] = row[1029];
    w0s[6*512+c] = row[1030]; w0s[7*512+c] = row[1031]; w0s[8*512+c] = row[1032];
    w0s[9*512+c] = row[1033];
    const float* rn = Wn + (size_t)c*1030;
#pragma unroll
    for (int j = 0; j < 6; j++) w0n[j*512+c] = rn[512+j];
  } else {
    int bl = b - 129;
    int e = bl*256 + t;
    int pred = 0;
    if (e < EN) {
      int d = dst[e];
      atomicAdd(&cnt[d], 1.0f);   // integer-valued: exact, order-free
      pred = (d % NVP) == 0;
      if (pred) need[src[e]] = 1;
    }
    int c = blockCount(pred, ws4);
    if (t == 0) bcnt[bl] = c;
  }
}

__global__ __launch_bounds__(256) void cntE0N1_k(const int* dst, const int* need,
                                                 int* bcntE, int* bcntN) {
  __shared__ int ws4[4];
  int b = blockIdx.x;
  if (b < EBLK) {
    int e = b*256 + threadIdx.x;
    int pred = (e < EN) && need[dst[e]];
    int c = blockCount(pred, ws4);
    if (threadIdx.x == 0) bcntE[b] = c;
  } else {
    int n = (b-EBLK)*256 + threadIdx.x;
    int pred = (n < NN) && need[n];
    int c = blockCount(pred, ws4);
    if (threadIdx.x == 0) bcntN[b-EBLK] = c;
  }
}
__global__ __launch_bounds__(256) void emit3s_k(const int* src, const int* dst,
                                                const int* need,
                                                const int* bcntS, int* listES,
                                                const int* bcntE, int* listE0, int* posOf,
                                                const int* bcntN, int* listN1, int* posN,
                                                int* tot) {
  __shared__ int red[4];
  __shared__ int ws4[4];
  int b = blockIdx.x;
  const int* bcnt; int bl, nblk, seg;
  if (b < EBLK)        { seg = 0; bl = b;          bcnt = bcntS; nblk = EBLK; }
  else if (b < 2*EBLK) { seg = 1; bl = b - EBLK;   bcnt = bcntE; nblk = EBLK; }
  else                 { seg = 2; bl = b - 2*EBLK; bcnt = bcntN; nblk = NBLK; }
  int boff = blockSumN(bcnt, bl, red);
  if (bl == 0) {
    int tt = blockSumN(bcnt, nblk, red);
    if (threadIdx.x == 0) tot[seg] = tt;
  }
  if (seg == 0) {
    int e = bl*256 + threadIdx.x;
    int pred = (e < EN) && (dst[e] % NVP == 0);
    int rank = blockRank(pred, ws4);
    if (pred) { int pos = boff + rank; if (pos < CAP_ES) listES[pos] = e; }
  } else if (seg == 1) {
    int e = bl*256 + threadIdx.x;
    int pred = (e < EN) && need[dst[e]];
    int rank = blockRank(pred, ws4);
    if (pred) { int pos = boff + rank;
      if (pos < CAP_E0) { listE0[pos] = e; posOf[e] = pos; } }
  } else {
    int n = bl*256 + threadIdx.x;
    int pred = (n < NN) && need[n];
    int rank = blockRank(pred, ws4);
    if (pred) { int pos = boff + rank;
      if (pos < CAP_N1) { listN1[pos] = n; posN[n] = pos; } }
  }
}

// P0 edge L0 via Ts/Td partial tables, float4
__global__ __launch_bounds__(128) void edge0_k(const int* nE0p, const int* listE0,
                                               const int* src, const int* dst,
                                               const float* pbTs, const float* pbTd,
                                               const float* la, const float* w0s,
                                               const float* b0, float* h0c) {
  int i = blockIdx.x;
  int n0 = *nE0p; if (n0 > CAP_E0) n0 = CAP_E0;
  if (i >= n0) return;
  int tid = threadIdx.x;
  int e = listE0[i];
  int s = src[e], d = dst[e];
  float a0 = la[s*3], a1 = la[s*3+1], a2 = la[s*3+2];
  float c0 = la[d*3], c1 = la[d*3+1], c2 = la[d*3+2];
  float r0 = c0-a0, r1 = c1-a1, r2 = c2-a2;
  float dn = sqrtf(r0*r0 + r1*r1 + r2*r2);
  const float g = LRc / 32.1558704423f; // sqrt(1034)
  int sr = s & 63, dr = d & 63;
  int c4 = tid*4;
  float ys[4] = {0.f,0.f,0.f,0.f};
#pragma unroll
  for (int z = 0; z < SK_T; z++) {
    float4 vs = *(const float4*)&pbTs[((size_t)z*64 + sr)*512 + c4];
    float4 vd = *(const float4*)&pbTd[((size_t)z*64 + dr)*512 + c4];
    ys[0] += vs.x + vd.x; ys[1] += vs.y + vd.y;
    ys[2] += vs.z + vd.z; ys[3] += vs.w + vd.w;
  }
  float cf[10] = {a0,a1,a2,c0,c1,c2,r0,r1,r2,dn};
#pragma unroll
  for (int j = 0; j < 10; j++) {
    float4 wv = *(const float4*)&w0s[j*512 + c4];
    ys[0] += cf[j]*wv.x; ys[1] += cf[j]*wv.y; ys[2] += cf[j]*wv.z; ys[3] += cf[j]*wv.w;
  }
  float4 bv = *(const float4*)&b0[c4];
  float bb[4] = {bv.x, bv.y, bv.z, bv.w};
#pragma unroll
  for (int j = 0; j < 4; j++) {
    float y = ys[j]*g + bb[j]*LRc;
    ys[j] = (y > 0.f ? y : 0.2f*y) * SQ2;
  }
  *(float4*)&h0c[(size_t)i*512 + c4] = make_float4(ys[0],ys[1],ys[2],ys[3]);
}

extern "C" void kernel_launch(void* const* d_in, const int* in_sizes, int n_in,
                              void* d_out, int out_size, void* d_ws, size_t ws_size,
                              hipStream_t stream) {
  const float* z     = (const float*)d_in[0];
  const float* la    = (const float*)d_in[1];
  const int*   ei    = (const int*)  d_in[2];
  const float* p0ew0 = (const float*)d_in[3];
  const float* p0eb0 = (const float*)d_in[4];
  const float* p0ew1 = (const float*)d_in[5];
  const float* p0eb1 = (const float*)d_in[6];
  const float* p0nw0 = (const float*)d_in[7];
  const float* p0nb0 = (const float*)d_in[8];
  const float* p0nw1 = (const float*)d_in[9];
  const float* p0nb1 = (const float*)d_in[10];
  const float* p1ew0 = (const float*)d_in[11];
  const float* p1eb0 = (const float*)d_in[12];
  const float* p1ew1 = (const float*)d_in[13];
  const float* p1eb1 = (const float*)d_in[14];
  const float* p1nw0 = (const float*)d_in[15];
  const float* p1nb0 = (const float*)d_in[16];
  const float* p1nw1 = (const float*)d_in[17];
  const float* p1nb1 = (const float*)d_in[18];
  const int* src = ei;
  const int* dst = ei + EN;

  char* ws = (char*)d_ws;
  size_t off = 0;
  auto al = [&](size_t bytes) -> void* {
    void* r = (void*)(ws + off);
    off += (bytes + 255) & ~(size_t)255;
    return r;
  };
  // ---- zeroed region: atomic targets + need (1s-only writers) ----
  float* cnt    = (float*)al(NN*4);
  int*   need   = (int*)  al(NN*4);
  float* agg0c  = (float*)al((size_t)CAP_N1*512*4);
  float* agg1c  = (float*)al(64*512*4);
  size_t zEnd = off;
  // ---- written-before-read region ----
  int*   tot    = (int*)  al(3*4);
  int*   posN   = (int*)  al(NN*4);
  int*   posOf  = (int*)  al((size_t)EN*4);
  int*   bcntS  = (int*)  al(EBLK*4);
  int*   bcntE  = (int*)  al(EBLK*4);
  int*   bcntN  = (int*)  al(NBLK*4);
  int*   listES = (int*)  al(CAP_ES*4);
  int*   listN1 = (int*)  al(CAP_N1*4);
  int*   listE0 = (int*)  al(CAP_E0*4);
  float* zn     = (float*)al(64*512*4);
  float* w0s    = (float*)al(10*512*4);
  float* w0n    = (float*)al(6*512*4);
  float* pbTs   = (float*)al((size_t)SK_T*64*512*4);
  float* pbTd   = (float*)al((size_t)SK_T*64*512*4);
  float* pbT0   = (float*)al((size_t)SK_T*64*512*4);
  float* h0c    = (float*)al((size_t)CAP_E0*512*4);
  float* ef0c   = (float*)al((size_t)CAP_E0*512*4);
  float* hn1    = (float*)al((size_t)CAP_N1*512*4);
  float* x1c    = (float*)al((size_t)CAP_N1*512*4);
  float* hs     = (float*)al((size_t)CAP_ES*512*4);
  float* hn64   = (float*)al(64*512*4);
  float* pbuf   = (float*)al((size_t)SK_GS*CAP_ES*512*4);  // gemmGS SK=6; tails reuse

  hipMemsetAsync(ws, 0, zEnd, stream);

  init_k<<<129 + EBLK, 256, 0, stream>>>(z, zn, need, p0ew0, p0nw0, w0s, w0n,
                                         src, dst, cnt, bcntS);
  cntE0N1_k<<<EBLK+NBLK, 256, 0, stream>>>(dst, need, bcntE, bcntN);
  emit3s_k<<<2*EBLK+NBLK, 256, 0, stream>>>(src, dst, need, bcntS, listES,
                                            bcntE, listE0, posOf,
                                            bcntN, listN1, posN, tot);
  {
    TABP q{zn, p0ew0, p0nw0, pbTs, pbTd, pbT0};
    tab_k<<<dim3(2, 24, SK_T), 128, 0, stream>>>(q);
  }
  edge0_k<<<CAP_E0, 128, 0, stream>>>(tot+1, listE0, src, dst, pbTs, pbTd, la, w0s,
                                      p0eb0, h0c);

  // P0 edge L1 (MFMA fused EPI1): K=512 -> ef0c + atomic agg0c
  {
    GMF p{}; p.W = p0ew1; p.Wld = 512; p.Woff = 0; p.Astride = 512;
    p.K = 512; p.Mcap = CAP_E0; p.Mdev = tot+1; p.Ain = h0c;
    p.f.bias = p0eb1; p.f.gain = LRc/sqrtf(512.f);
    p.f.rmap = listE0; p.f.dst = dst; p.f.posN = posN;
    p.f.outp = ef0c; p.f.atomp = agg0c;
    gemmMF<1,0,1><<<dim3(CAP_E0/64, 8), 256, 0, stream>>>(p);
  }
  // P0 node L0 (MFMA fused EPI7, row-scaled, scalar-W): K=512 over agg0c -> hn1
  {
    GMF p{}; p.W = p0nw0; p.Wld = 1030; p.Woff = 518; p.Astride = 512;
    p.K = 512; p.Mcap = CAP_N1; p.Mdev = tot+2;
    p.Ain = agg0c; p.cnt = cnt; p.listN1 = listN1;
    p.f.bias = p0nb0; p.f.gain = LRc/sqrtf(1030.f);
    p.f.T0p = pbT0; p.f.la = la; p.f.cnt = cnt; p.f.w0n = w0n; p.f.rmap = listN1;
    p.f.outp = hn1;
    gemmMF<0,1,7><<<dim3(CAP_N1/64, 8), 256, 0, stream>>>(p);
  }
  // P0 node L1 (MFMA fused EPI0) -> x1c
  {
    GMF p{}; p.W = p0nw1; p.Wld = 512; p.Woff = 0; p.Astride = 512;
    p.K = 512; p.Mcap = CAP_N1; p.Mdev = tot+2; p.Ain = hn1;
    p.f.bias = p0nb1; p.f.gain = LRc/sqrtf(512.f); p.f.outp = x1c;
    gemmMF<1,0,0><<<dim3(CAP_N1/64, 8), 256, 0, stream>>>(p);
  }
  // P1 edge L0 (MFMA gather, split-K SK=6): K=1536 -> pbuf -> hs
  {
    GGS p{}; p.W = p1ew0; p.x1c = x1c; p.ef0c = ef0c;
    p.listES = listES; p.src = src; p.dst = dst; p.posN = posN; p.posOf = posOf;
    p.Mdev = tot+0; p.pbuf = pbuf; p.KC = 256;
    gemmGS<<<dim3(CAP_ES/64, 8, SK_GS), 256, 0, stream>>>(p);
    EPS e{}; e.pbuf = pbuf; e.SK = SK_GS; e.Mdev = tot+0;
    e.bias = p1eb0; e.gain = LRc/sqrtf(1536.f); e.outp = hs;
    epiS_k<<<(CAP_ES*128)/256, 256, 0, stream>>>(e);
  }
  // P1 edge L1 (MFMA fused EPI2): K=512 -> atomic agg1c
  {
    GMF p{}; p.W = p1ew1; p.Wld = 512; p.Woff = 0; p.Astride = 512;
    p.K = 512; p.Mcap = CAP_ES; p.Mdev = tot+0; p.Ain = hs;
    p.f.bias = p1eb1; p.f.gain = LRc/sqrtf(512.f);
    p.f.rmap = listES; p.f.dst = dst; p.f.atomp = agg1c;
    gemmMF<1,0,2><<<dim3(CAP_ES/64, 8), 256, 0, stream>>>(p);
  }
  // P1 node L0 (f32 split-K SK=8): K=1024 -> pbuf -> hn64
  {
    GTP p{}; p.W = p1nw0; p.x1c = x1c; p.agg1c = agg1c; p.cnt = cnt;
    p.posN = posN; p.pbuf = pbuf; p.KC = 128;
    gemmT<<<dim3(2, 8, 8), 128, 0, stream>>>(p);
    EPP e{}; e.pbuf = pbuf; e.SK = 8; e.bias = p1nb0;
    e.gain = LRc/sqrtf(1024.f); e.outp = hn64;
    epi_k<0><<<(64*128)/256, 256, 0, stream>>>(e);
  }
  // P1 node L1 (f32 split-K SK=4): K=512 -> pbuf -> d_out (14x tiled)
  {
    GPP p{}; p.W = p1nw1; p.Ain = hn64; p.pbuf = pbuf; p.KC = 128;
    gemmP<<<dim3(2, 8, 4), 128, 0, stream>>>(p);
    EPP e{}; e.pbuf = pbuf; e.SK = 4; e.bias = p1nb1;
    e.gain = LRc/sqrtf(512.f); e.outp = (float*)d_out;
    epi_k<8><<<(64*128)/256, 256, 0, stream>>>(e);
  }
}